// Round 6
// baseline (329.497 us; speedup 1.0000x reference)
//
#include <hip/hip_runtime.h>
#include <math.h>

// Problem constants: B=4, L=S=2048, H=16, E=D=64.
#define BB 4
#define LL 2048
#define HH 16
#define EE 64
#define HE (HH*EE)   // 1024 elements per (b,l) row

constexpr int QBLK  = 128;   // q rows per block (8 waves x 16 rows)
constexpr int KVBLK = 64;    // keys per LDS tile
constexpr int NW    = 8;     // waves per block
constexpr int NQT   = LL / QBLK;  // 16
constexpr int LDK   = 72;    // LDS row stride in shorts (64 + 8 pad)
constexpr float SCL2E = 0.18033688011112042f; // (1/sqrt(64)) * log2(e)
constexpr float DEFER_THR = 8.0f;  // defer-max threshold (exp2 domain): P <= 2^8

typedef short short8 __attribute__((ext_vector_type(8)));
typedef float f32x4  __attribute__((ext_vector_type(4)));

#define MFMA(a, b, c) __builtin_amdgcn_mfma_f32_16x16x32_bf16((a), (b), (c), 0, 0, 0)

static __device__ __forceinline__ unsigned short f2bf(float f) {
    unsigned u = __float_as_uint(f);
    return (unsigned short)((u + 0x7FFFu + ((u >> 16) & 1u)) >> 16);  // RNE
}

// Causal flash attention, bf16 MFMA. Straight-bf16 QK^T (absmax headroom 4.5x
// measured in round 4 justified dropping the hi/lo split: halves MFMA count,
// cuts staging VALU, frees 9.2KB LDS -> 4 blocks/CU).
__global__ __launch_bounds__(512, 8)
void attn_mfma(const float* __restrict__ Q, const float* __restrict__ K,
               const float* __restrict__ V, float* __restrict__ O)
{
    __shared__ short Ks[KVBLK * LDK];        // K bf16, [key][e], padded
    __shared__ short Vt[EE * LDK];           // V^T bf16, [d][key], XOR-swizzled cols
    __shared__ short Pl[NW * 16 * LDK];      // per-wave P, [q][key], padded

    const int bid = blockIdx.x;
    const int qt  = (NQT - 1) - (bid >> 6);       // descending work order
    const int bh  = bid & 63;
    const int b   = bh >> 4, h = bh & 15;
    const size_t base = (size_t)b * LL * HE + (size_t)h * EE;

    const int tid  = threadIdx.x;
    const int wave = tid >> 6, lane = tid & 63;
    const int g    = lane >> 4, c = lane & 15;    // quarter-wave group, col lane

    const int q0 = qt * QBLK + wave * 16;         // this wave's first q row

    // ---- Q fragment in registers: A-frag lane holds Q[q0 + c][ec*32 + 8g + i]
    short8 qf[2];
    {
        const float* qp = Q + base + (size_t)(q0 + c) * HE + 8 * g;
        #pragma unroll
        for (int ec = 0; ec < 2; ++ec) {
            float4 f0 = *(const float4*)(qp + ec * 32);
            float4 f1 = *(const float4*)(qp + ec * 32 + 4);
            float fv[8] = {f0.x, f0.y, f0.z, f0.w, f1.x, f1.y, f1.z, f1.w};
            #pragma unroll
            for (int i = 0; i < 8; ++i)
                qf[ec][i] = (short)f2bf(fv[i] * SCL2E);
        }
    }

    f32x4 o[4];
    #pragma unroll
    for (int db = 0; db < 4; ++db)
        #pragma unroll
        for (int j = 0; j < 4; ++j) o[db][j] = 0.0f;
    float m_r[4] = {-INFINITY, -INFINITY, -INFINITY, -INFINITY};
    float l_r[4] = {0.f, 0.f, 0.f, 0.f};

    const int ntile = 2 * qt + 2;
    const int srow = tid >> 3;          // staging: key row 0..63
    const int scc  = (tid & 7) * 8;     // staging: 8-elem col chunk

    for (int t = 0; t < ntile; ++t) {
        const int j0 = t * KVBLK;

        __syncthreads();  // previous tile fully consumed
        // ---- stage K and V^T (swizzled): coalesced 32B global chunks
        {
            const float* kp = K + base + (size_t)(j0 + srow) * HE + scc;
            float4 a0 = *(const float4*)(kp);
            float4 a1 = *(const float4*)(kp + 4);
            float fv[8] = {a0.x, a0.y, a0.z, a0.w, a1.x, a1.y, a1.z, a1.w};
            short8 hv;
            #pragma unroll
            for (int i = 0; i < 8; ++i) hv[i] = (short)f2bf(fv[i]);
            *(short8*)(&Ks[srow * LDK + scc]) = hv;

            const float* vp = V + base + (size_t)(j0 + srow) * HE + scc;
            float4 b0 = *(const float4*)(vp);
            float4 b1 = *(const float4*)(vp + 4);
            float gv[8] = {b0.x, b0.y, b0.z, b0.w, b1.x, b1.y, b1.z, b1.w};
            #pragma unroll
            for (int i = 0; i < 8; ++i) {
                const int d = scc + i;
                const int col = srow ^ (((d >> 3) & 7) << 3);  // XOR swizzle (8-elem gran)
                Vt[d * LDK + col] = (short)f2bf(gv[i]);
            }
        }
        __syncthreads();

        if (j0 <= q0 + 15) {                        // else: this wave fully masked
            // Mask needed unless the tile's LAST key <= the wave's FIRST row.
            // (j0 <= q0 always holds here: both are multiples of 16 and
            //  j0 <= q0+15 -> every row has >= 1 valid key, tm stays finite.)
            const bool diag = (j0 + KVBLK - 1) > q0;

            // ---- QK^T: S[16q x 64k], D-layout row=4g+r, col=c
            f32x4 s[4];
            __builtin_amdgcn_s_setprio(1);
            #pragma unroll
            for (int kb = 0; kb < 4; ++kb) {
                f32x4 acc; acc[0]=0.f; acc[1]=0.f; acc[2]=0.f; acc[3]=0.f;
                const int roff = (kb * 16 + c) * LDK + 8 * g;
                short8 k0 = *(const short8*)(&Ks[roff]);
                short8 k1 = *(const short8*)(&Ks[roff + 32]);
                acc = MFMA(qf[0], k0, acc);
                acc = MFMA(qf[1], k1, acc);
                s[kb] = acc;
            }
            __builtin_amdgcn_s_setprio(0);

            // ---- mask + row max (reduce over 16 key-lanes; uniform per row after)
            float tm[4];
            #pragma unroll
            for (int r = 0; r < 4; ++r) {
                if (diag) {
                    const int qrow = q0 + 4 * g + r;
                    #pragma unroll
                    for (int kb = 0; kb < 4; ++kb)
                        if (j0 + kb * 16 + c > qrow) s[kb][r] = -INFINITY;
                }
                tm[r] = fmaxf(fmaxf(s[0][r], s[1][r]), fmaxf(s[2][r], s[3][r]));
                #pragma unroll
                for (int xm = 1; xm <= 8; xm <<= 1)
                    tm[r] = fmaxf(tm[r], __shfl_xor(tm[r], xm));
            }

            // ---- online softmax (defer-max, THR=8 in exp2 domain) + P->bf16->LDS
            #pragma unroll
            for (int r = 0; r < 4; ++r) {
                const float nm = fmaxf(m_r[r], tm[r]);
                if (nm - m_r[r] > DEFER_THR) {       // rescale (rare after tile 0)
                    const float corr = __builtin_amdgcn_exp2f(m_r[r] - nm); // -inf -> 0
                    l_r[r] *= corr;
                    #pragma unroll
                    for (int db = 0; db < 4; ++db) o[db][r] *= corr;
                    m_r[r] = nm;
                }
                #pragma unroll
                for (int kb = 0; kb < 4; ++kb) {
                    const float p = __builtin_amdgcn_exp2f(s[kb][r] - m_r[r]); // <= 2^8
                    l_r[r] += p;                      // fp32 denom (unrounded)
                    Pl[(wave * 16 + 4 * g + r) * LDK + kb * 16 + c] = (short)f2bf(p);
                }
            }

            // ---- PV: O[16q x 64d] += P * V   (A=P from LDS, B=V^T rows)
            #pragma unroll
            for (int kc = 0; kc < 2; ++kc) {
                short8 pa = *(const short8*)(&Pl[(wave * 16 + c) * LDK + kc * 32 + 8 * g]);
                __builtin_amdgcn_s_setprio(1);
                #pragma unroll
                for (int db = 0; db < 4; ++db) {
                    const int d  = db * 16 + c;
                    const int k0 = (kc * 32 + 8 * g) ^ (((d >> 3) & 7) << 3);
                    short8 vb = *(const short8*)(&Vt[d * LDK + k0]);
                    o[db] = MFMA(pa, vb, o[db]);
                }
                __builtin_amdgcn_s_setprio(0);
            }
        }
    }

    // ---- epilogue: reduce denominator across key-lanes, normalize, store
    #pragma unroll
    for (int r = 0; r < 4; ++r) {
        float ls = l_r[r];
        #pragma unroll
        for (int xm = 1; xm <= 8; xm <<= 1) ls += __shfl_xor(ls, xm);
        const float inv = 1.0f / ls;
        float* op = O + base + (size_t)(q0 + 4 * g + r) * HE + c;
        #pragma unroll
        for (int db = 0; db < 4; ++db)
            op[db * 16] = o[db][r] * inv;
    }
}

extern "C" void kernel_launch(void* const* d_in, const int* in_sizes, int n_in,
                              void* d_out, int out_size, void* d_ws, size_t ws_size,
                              hipStream_t stream) {
    const float* Q = (const float*)d_in[0];
    const float* K = (const float*)d_in[1];
    const float* V = (const float*)d_in[2];
    float* Out = (float*)d_out;

    dim3 grid(BB * HH * NQT);   // 1024 blocks, high-work q-tiles first
    dim3 block(512);
    hipLaunchKernelGGL(attn_mfma, grid, block, 0, stream, Q, K, V, Out);
}

// Round 10
// 225.423 us; speedup vs baseline: 1.4617x; 1.4617x over previous
//
#include <hip/hip_runtime.h>
#include <math.h>

// Problem constants: B=4, L=S=2048, H=16, E=D=64.
#define BB 4
#define LL 2048
#define HH 16
#define EE 64
#define HE (HH*EE)   // 1024 elements per (b,l) row

constexpr int QBLK  = 128;   // q rows per block (8 waves x 16 rows)
constexpr int KVBLK = 64;    // keys per LDS tile
constexpr int NW    = 8;     // waves per block
constexpr int NQT   = LL / QBLK;  // 16
constexpr int LDK   = 72;    // LDS row stride in shorts (64 + 8 pad)
constexpr float SCL2E = 0.18033688011112042f; // (1/sqrt(64)) * log2(e)
constexpr float DEFER_THR = 8.0f;  // defer-max threshold (exp2 domain): P <= 2^8

typedef short short8 __attribute__((ext_vector_type(8)));
typedef float f32x4  __attribute__((ext_vector_type(4)));

#define MFMA(a, b, c) __builtin_amdgcn_mfma_f32_16x16x32_bf16((a), (b), (c), 0, 0, 0)

static __device__ __forceinline__ unsigned short f2bf(float f) {
    unsigned u = __float_as_uint(f);
    return (unsigned short)((u + 0x7FFFu + ((u >> 16) & 1u)) >> 16);  // RNE
}

// Causal flash attention, bf16 MFMA, straight-bf16 QK^T.
// __launch_bounds__(512,4): round 6 measured that (512,8) caps VGPR at 64 ->
// compiler spills to scratch (FETCH +200MB, WRITE +82MB, dur 163->240us).
// (512,4) gives VGPR=60 naturally (round 4) -- no spill, and HW can still
// co-schedule 4 blocks/CU since 60 <= 64 and LDS is 36.9KB.
__global__ __launch_bounds__(512, 4)
void attn_mfma(const float* __restrict__ Q, const float* __restrict__ K,
               const float* __restrict__ V, float* __restrict__ O)
{
    __shared__ short Ks[KVBLK * LDK];        // K bf16, [key][e], padded
    __shared__ short Vt[EE * LDK];           // V^T bf16, [d][key], XOR-swizzled cols
    __shared__ short Pl[NW * 16 * LDK];      // per-wave P, [q][key], padded

    const int bid = blockIdx.x;
    const int qt  = (NQT - 1) - (bid >> 6);       // descending work order
    const int bh  = bid & 63;
    const int b   = bh >> 4, h = bh & 15;
    const size_t base = (size_t)b * LL * HE + (size_t)h * EE;

    const int tid  = threadIdx.x;
    const int wave = tid >> 6, lane = tid & 63;
    const int g    = lane >> 4, c = lane & 15;    // quarter-wave group, col lane

    const int q0 = qt * QBLK + wave * 16;         // this wave's first q row

    // ---- Q fragment in registers: A-frag lane holds Q[q0 + c][ec*32 + 8g + i]
    short8 qf[2];
    {
        const float* qp = Q + base + (size_t)(q0 + c) * HE + 8 * g;
        #pragma unroll
        for (int ec = 0; ec < 2; ++ec) {
            float4 f0 = *(const float4*)(qp + ec * 32);
            float4 f1 = *(const float4*)(qp + ec * 32 + 4);
            float fv[8] = {f0.x, f0.y, f0.z, f0.w, f1.x, f1.y, f1.z, f1.w};
            #pragma unroll
            for (int i = 0; i < 8; ++i)
                qf[ec][i] = (short)f2bf(fv[i] * SCL2E);
        }
    }

    f32x4 o[4];
    #pragma unroll
    for (int db = 0; db < 4; ++db)
        #pragma unroll
        for (int j = 0; j < 4; ++j) o[db][j] = 0.0f;
    float m_r[4] = {-INFINITY, -INFINITY, -INFINITY, -INFINITY};
    float l_r[4] = {0.f, 0.f, 0.f, 0.f};

    const int ntile = 2 * qt + 2;
    const int srow = tid >> 3;          // staging: key row 0..63
    const int scc  = (tid & 7) * 8;     // staging: 8-elem col chunk

    for (int t = 0; t < ntile; ++t) {
        const int j0 = t * KVBLK;

        __syncthreads();  // previous tile fully consumed
        // ---- stage K and V^T (swizzled): coalesced 32B global chunks
        {
            const float* kp = K + base + (size_t)(j0 + srow) * HE + scc;
            float4 a0 = *(const float4*)(kp);
            float4 a1 = *(const float4*)(kp + 4);
            float fv[8] = {a0.x, a0.y, a0.z, a0.w, a1.x, a1.y, a1.z, a1.w};
            short8 hv;
            #pragma unroll
            for (int i = 0; i < 8; ++i) hv[i] = (short)f2bf(fv[i]);
            *(short8*)(&Ks[srow * LDK + scc]) = hv;

            const float* vp = V + base + (size_t)(j0 + srow) * HE + scc;
            float4 b0 = *(const float4*)(vp);
            float4 b1 = *(const float4*)(vp + 4);
            float gv[8] = {b0.x, b0.y, b0.z, b0.w, b1.x, b1.y, b1.z, b1.w};
            #pragma unroll
            for (int i = 0; i < 8; ++i) {
                const int d = scc + i;
                const int col = srow ^ (((d >> 3) & 7) << 3);  // XOR swizzle (8-elem gran)
                Vt[d * LDK + col] = (short)f2bf(gv[i]);
            }
        }
        __syncthreads();

        if (j0 <= q0 + 15) {                        // else: this wave fully masked
            // Mask needed unless the tile's LAST key <= the wave's FIRST row.
            const bool diag = (j0 + KVBLK - 1) > q0;

            // ---- QK^T: S[16q x 64k], D-layout row=4g+r, col=c
            f32x4 s[4];
            __builtin_amdgcn_s_setprio(1);
            #pragma unroll
            for (int kb = 0; kb < 4; ++kb) {
                f32x4 acc; acc[0]=0.f; acc[1]=0.f; acc[2]=0.f; acc[3]=0.f;
                const int roff = (kb * 16 + c) * LDK + 8 * g;
                short8 k0 = *(const short8*)(&Ks[roff]);
                short8 k1 = *(const short8*)(&Ks[roff + 32]);
                acc = MFMA(qf[0], k0, acc);
                acc = MFMA(qf[1], k1, acc);
                s[kb] = acc;
            }
            __builtin_amdgcn_s_setprio(0);

            // ---- mask + row max (reduce over 16 key-lanes; uniform per row after)
            float tm[4];
            #pragma unroll
            for (int r = 0; r < 4; ++r) {
                if (diag) {
                    const int qrow = q0 + 4 * g + r;
                    #pragma unroll
                    for (int kb = 0; kb < 4; ++kb)
                        if (j0 + kb * 16 + c > qrow) s[kb][r] = -INFINITY;
                }
                tm[r] = fmaxf(fmaxf(s[0][r], s[1][r]), fmaxf(s[2][r], s[3][r]));
                #pragma unroll
                for (int xm = 1; xm <= 8; xm <<= 1)
                    tm[r] = fmaxf(tm[r], __shfl_xor(tm[r], xm));
            }

            // ---- online softmax (defer-max, THR=8 in exp2 domain) + P->bf16->LDS
            #pragma unroll
            for (int r = 0; r < 4; ++r) {
                const float nm = fmaxf(m_r[r], tm[r]);
                if (nm - m_r[r] > DEFER_THR) {       // rescale (rare after tile 0)
                    const float corr = __builtin_amdgcn_exp2f(m_r[r] - nm); // -inf -> 0
                    l_r[r] *= corr;
                    #pragma unroll
                    for (int db = 0; db < 4; ++db) o[db][r] *= corr;
                    m_r[r] = nm;
                }
                #pragma unroll
                for (int kb = 0; kb < 4; ++kb) {
                    const float p = __builtin_amdgcn_exp2f(s[kb][r] - m_r[r]); // <= 2^8
                    l_r[r] += p;                      // fp32 denom (unrounded)
                    Pl[(wave * 16 + 4 * g + r) * LDK + kb * 16 + c] = (short)f2bf(p);
                }
            }

            // ---- PV: O[16q x 64d] += P * V   (A=P from LDS, B=V^T rows)
            #pragma unroll
            for (int kc = 0; kc < 2; ++kc) {
                short8 pa = *(const short8*)(&Pl[(wave * 16 + c) * LDK + kc * 32 + 8 * g]);
                __builtin_amdgcn_s_setprio(1);
                #pragma unroll
                for (int db = 0; db < 4; ++db) {
                    const int d  = db * 16 + c;
                    const int k0 = (kc * 32 + 8 * g) ^ (((d >> 3) & 7) << 3);
                    short8 vb = *(const short8*)(&Vt[d * LDK + k0]);
                    o[db] = MFMA(pa, vb, o[db]);
                }
                __builtin_amdgcn_s_setprio(0);
            }
        }
    }

    // ---- epilogue: reduce denominator across key-lanes, normalize, store
    #pragma unroll
    for (int r = 0; r < 4; ++r) {
        float ls = l_r[r];
        #pragma unroll
        for (int xm = 1; xm <= 8; xm <<= 1) ls += __shfl_xor(ls, xm);
        const float inv = 1.0f / ls;
        float* op = O + base + (size_t)(q0 + 4 * g + r) * HE + c;
        #pragma unroll
        for (int db = 0; db < 4; ++db)
            op[db * 16] = o[db][r] * inv;
    }
}

extern "C" void kernel_launch(void* const* d_in, const int* in_sizes, int n_in,
                              void* d_out, int out_size, void* d_ws, size_t ws_size,
                              hipStream_t stream) {
    const float* Q = (const float*)d_in[0];
    const float* K = (const float*)d_in[1];
    const float* V = (const float*)d_in[2];
    float* Out = (float*)d_out;

    dim3 grid(BB * HH * NQT);   // 1024 blocks, high-work q-tiles first
    dim3 block(512);
    hipLaunchKernelGGL(attn_mfma, grid, block, 0, stream, Q, K, V, Out);
}

// Round 12
// 212.988 us; speedup vs baseline: 1.5470x; 1.0584x over previous
//
#include <hip/hip_runtime.h>
#include <math.h>

// Problem constants: B=4, L=S=2048, H=16, E=D=64.
#define BB 4
#define LL 2048
#define HH 16
#define EE 64
#define HE (HH*EE)   // 1024 elements per (b,l) row

constexpr int QBLK  = 128;   // q rows per block (8 waves x 16 rows)
constexpr int KVBLK = 64;    // keys per LDS tile
constexpr int NW    = 8;     // waves per block
constexpr int NQT   = LL / QBLK;  // 16
constexpr int NT    = LL / KVBLK; // 32 KV tiles per (b,h)
constexpr int LDK   = 72;    // Pl LDS row stride in shorts (64 + 8 pad)
constexpr float SCL2E = 0.18033688011112042f; // (1/sqrt(64)) * log2(e)
constexpr float DEFER_THR = 8.0f;  // defer-max threshold (exp2 domain): P <= 2^8

typedef short short8 __attribute__((ext_vector_type(8)));
typedef float f32x4  __attribute__((ext_vector_type(4)));

#define MFMA(a, b, c) __builtin_amdgcn_mfma_f32_16x16x32_bf16((a), (b), (c), 0, 0, 0)

// global_load_lds: 16B per lane, per-lane GLOBAL addr, wave-uniform LDS base
// (writes lds_base + lane*16). Swizzle must be pre-applied to the SOURCE
// (G21: linear dest + inverse-swizzled source + swizzled read).
#define GLD_LDS16(gp, lp)                                                     \
    __builtin_amdgcn_global_load_lds(                                         \
        (const __attribute__((address_space(1))) void*)(gp),                  \
        (__attribute__((address_space(3))) void*)(lp), 16, 0, 0)

static __device__ __forceinline__ unsigned short f2bf(float f) {
    unsigned u = __float_as_uint(f);
    return (unsigned short)((u + 0x7FFFu + ((u >> 16) & 1u)) >> 16);  // RNE
}

// ---------------------------------------------------------------------------
// Prepass: K -> bf16, XOR-pre-swizzled, tiled [bh][t][key][e'];
//          V -> bf16, tile-TRANSPOSED [bh][t][d][key'], same pre-swizzle.
// Runs once per launch; removes the 8.5x-redundant per-block convert+transpose.
// ---------------------------------------------------------------------------
__global__ __launch_bounds__(512, 2)
void prepass_cvt(const float* __restrict__ K, const float* __restrict__ V,
                 short* __restrict__ Kw, short* __restrict__ Vw)
{
    __shared__ short Vs[KVBLK][74];      // [key][d], pad 74 to spread banks
    const int bid = blockIdx.x;          // bh*NT + t
    const int bh  = bid >> 5, t = bid & 31;
    const int b   = bh >> 4, h = bh & 15;
    const int j0  = t * KVBLK;
    const int tid = threadIdx.x;
    const int row = tid >> 3;            // key (phase 1) / d (phase 2), 0..63
    const int ch8 = (tid & 7) * 8;       // 8-elem chunk
    const size_t gbase = (size_t)b * LL * HE + (size_t)h * EE;
    const size_t obase = (size_t)bid * (64 * 64);   // 4096 shorts per tile

    // ---- K: convert + swizzled store (layout unchanged: [key][e'])
    {
        const float* kp = K + gbase + (size_t)(j0 + row) * HE + ch8;
        float4 a0 = *(const float4*)kp, a1 = *(const float4*)(kp + 4);
        float fv[8] = {a0.x,a0.y,a0.z,a0.w,a1.x,a1.y,a1.z,a1.w};
        short8 hv;
        #pragma unroll
        for (int i = 0; i < 8; ++i) hv[i] = (short)f2bf(fv[i]);
        *(short8*)(Kw + obase + row * 64 + (ch8 ^ ((row & 7) * 8))) = hv;
    }
    // ---- V: convert into LDS [key][d]
    {
        const float* vp = V + gbase + (size_t)(j0 + row) * HE + ch8;
        float4 b0 = *(const float4*)vp, b1 = *(const float4*)(vp + 4);
        float gv[8] = {b0.x,b0.y,b0.z,b0.w,b1.x,b1.y,b1.z,b1.w};
        short8 vv;
        #pragma unroll
        for (int i = 0; i < 8; ++i) vv[i] = (short)f2bf(gv[i]);
        *(short8*)(&Vs[row][ch8]) = vv;
    }
    __syncthreads();
    // ---- transpose out: this thread owns d=row, keys ch8..ch8+7
    {
        short8 ov;
        #pragma unroll
        for (int i = 0; i < 8; ++i) ov[i] = Vs[ch8 + i][row];
        *(short8*)(Vw + obase + row * 64 + (ch8 ^ ((row & 7) * 8))) = ov;
    }
}

// ---------------------------------------------------------------------------
// Main: causal flash attention, bf16 MFMA. K/V staged from pre-converted
// bf16 workspace via global_load_lds (1 instr/wave/tensor/tile, zero VALU).
// ---------------------------------------------------------------------------
__global__ __launch_bounds__(512, 4)
void attn_fast(const float* __restrict__ Q, const short* __restrict__ Kw,
               const short* __restrict__ Vw, float* __restrict__ O)
{
    __shared__ alignas(16) short Ks[KVBLK * 64]; // [key][e'] swizzled image
    __shared__ alignas(16) short Vt[EE * 64];    // [d][key'] swizzled image
    __shared__ short Pl[NW * 16 * LDK];          // per-wave P, [q][key], padded

    const int bid = blockIdx.x;
    const int qt  = (NQT - 1) - (bid >> 6);       // descending work order
    const int bh  = bid & 63;
    const int b   = bh >> 4, h = bh & 15;
    const size_t base = (size_t)b * LL * HE + (size_t)h * EE;

    const int tid  = threadIdx.x;
    const int wave = tid >> 6, lane = tid & 63;
    const int g    = lane >> 4, c = lane & 15;    // quarter-wave group, col lane
    const int swz  = (c & 7) * 8;                 // read-side XOR (matches prepass)

    const int q0 = qt * QBLK + wave * 16;         // this wave's first q row
    const size_t kvbase = (size_t)bh * (NT * 64 * 64);

    // ---- Q fragment in registers: A-frag lane holds Q[q0 + c][ec*32 + 8g + i]
    short8 qf[2];
    {
        const float* qp = Q + base + (size_t)(q0 + c) * HE + 8 * g;
        #pragma unroll
        for (int ec = 0; ec < 2; ++ec) {
            float4 f0 = *(const float4*)(qp + ec * 32);
            float4 f1 = *(const float4*)(qp + ec * 32 + 4);
            float fv[8] = {f0.x, f0.y, f0.z, f0.w, f1.x, f1.y, f1.z, f1.w};
            #pragma unroll
            for (int i = 0; i < 8; ++i)
                qf[ec][i] = (short)f2bf(fv[i] * SCL2E);
        }
    }

    f32x4 o[4];
    #pragma unroll
    for (int db = 0; db < 4; ++db)
        #pragma unroll
        for (int j = 0; j < 4; ++j) o[db][j] = 0.0f;
    float m_r[4] = {-INFINITY, -INFINITY, -INFINITY, -INFINITY};
    float l_r[4] = {0.f, 0.f, 0.f, 0.f};

    const int ntile = 2 * qt + 2;

    for (int t = 0; t < ntile; ++t) {
        const int j0 = t * KVBLK;

        __syncthreads();  // previous tile fully consumed
        // ---- stage K and V^T: one global_load_lds(16B) per wave per tensor
        {
            const size_t goff = kvbase + (size_t)t * 4096
                              + (size_t)(wave * 64 + lane) * 8;  // shorts
            GLD_LDS16(Kw + goff, Ks + wave * 512);
            GLD_LDS16(Vw + goff, Vt + wave * 512);
        }
        __syncthreads();  // compiler emits vmcnt(0) before this barrier

        if (j0 <= q0 + 15) {                        // else: this wave fully masked
            const bool diag = (j0 + KVBLK - 1) > q0;

            // ---- QK^T: S[16q x 64k], D-layout row=4g+r, col=c
            f32x4 s[4];
            __builtin_amdgcn_s_setprio(1);
            #pragma unroll
            for (int kb = 0; kb < 4; ++kb) {
                f32x4 acc; acc[0]=0.f; acc[1]=0.f; acc[2]=0.f; acc[3]=0.f;
                const int roff = (kb * 16 + c) * 64;
                short8 k0 = *(const short8*)(&Ks[roff + ((8 * g) ^ swz)]);
                short8 k1 = *(const short8*)(&Ks[roff + ((32 + 8 * g) ^ swz)]);
                acc = MFMA(qf[0], k0, acc);
                acc = MFMA(qf[1], k1, acc);
                s[kb] = acc;
            }
            __builtin_amdgcn_s_setprio(0);

            // ---- mask + row max (reduce over 16 key-lanes)
            float tm[4];
            #pragma unroll
            for (int r = 0; r < 4; ++r) {
                if (diag) {
                    const int qrow = q0 + 4 * g + r;
                    #pragma unroll
                    for (int kb = 0; kb < 4; ++kb)
                        if (j0 + kb * 16 + c > qrow) s[kb][r] = -INFINITY;
                }
                tm[r] = fmaxf(fmaxf(s[0][r], s[1][r]), fmaxf(s[2][r], s[3][r]));
                #pragma unroll
                for (int xm = 1; xm <= 8; xm <<= 1)
                    tm[r] = fmaxf(tm[r], __shfl_xor(tm[r], xm));
            }

            // ---- online softmax (defer-max, THR=8 in exp2 domain) + P->bf16->LDS
            #pragma unroll
            for (int r = 0; r < 4; ++r) {
                const float nm = fmaxf(m_r[r], tm[r]);
                if (nm - m_r[r] > DEFER_THR) {       // rescale (rare after tile 0)
                    const float corr = __builtin_amdgcn_exp2f(m_r[r] - nm); // -inf -> 0
                    l_r[r] *= corr;
                    #pragma unroll
                    for (int db = 0; db < 4; ++db) o[db][r] *= corr;
                    m_r[r] = nm;
                }
                #pragma unroll
                for (int kb = 0; kb < 4; ++kb) {
                    const float p = __builtin_amdgcn_exp2f(s[kb][r] - m_r[r]); // <= 2^8
                    l_r[r] += p;                      // fp32 denom (unrounded)
                    Pl[(wave * 16 + 4 * g + r) * LDK + kb * 16 + c] = (short)f2bf(p);
                }
            }

            // ---- PV: O[16q x 64d] += P * V   (A=P from LDS, B=V^T rows)
            #pragma unroll
            for (int kc = 0; kc < 2; ++kc) {
                short8 pa = *(const short8*)(&Pl[(wave * 16 + c) * LDK + kc * 32 + 8 * g]);
                __builtin_amdgcn_s_setprio(1);
                #pragma unroll
                for (int db = 0; db < 4; ++db) {
                    const int voff = (db * 16 + c) * 64 + ((kc * 32 + 8 * g) ^ swz);
                    short8 vb = *(const short8*)(&Vt[voff]);
                    o[db] = MFMA(pa, vb, o[db]);
                }
                __builtin_amdgcn_s_setprio(0);
            }
        }
    }

    // ---- epilogue: reduce denominator across key-lanes, normalize, store
    #pragma unroll
    for (int r = 0; r < 4; ++r) {
        float ls = l_r[r];
        #pragma unroll
        for (int xm = 1; xm <= 8; xm <<= 1) ls += __shfl_xor(ls, xm);
        const float inv = 1.0f / ls;
        float* op = O + base + (size_t)(q0 + 4 * g + r) * HE + c;
        #pragma unroll
        for (int db = 0; db < 4; ++db)
            op[db * 16] = o[db][r] * inv;
    }
}

// ---------------------------------------------------------------------------
// Fallback (round-10 kernel, measured 137us): used only if ws_size < 32 MiB.
// ---------------------------------------------------------------------------
__global__ __launch_bounds__(512, 4)
void attn_mfma(const float* __restrict__ Q, const float* __restrict__ K,
               const float* __restrict__ V, float* __restrict__ O)
{
    __shared__ short Ks[KVBLK * LDK];
    __shared__ short Vt[EE * LDK];
    __shared__ short Pl[NW * 16 * LDK];

    const int bid = blockIdx.x;
    const int qt  = (NQT - 1) - (bid >> 6);
    const int bh  = bid & 63;
    const int b   = bh >> 4, h = bh & 15;
    const size_t base = (size_t)b * LL * HE + (size_t)h * EE;

    const int tid  = threadIdx.x;
    const int wave = tid >> 6, lane = tid & 63;
    const int g    = lane >> 4, c = lane & 15;

    const int q0 = qt * QBLK + wave * 16;

    short8 qf[2];
    {
        const float* qp = Q + base + (size_t)(q0 + c) * HE + 8 * g;
        #pragma unroll
        for (int ec = 0; ec < 2; ++ec) {
            float4 f0 = *(const float4*)(qp + ec * 32);
            float4 f1 = *(const float4*)(qp + ec * 32 + 4);
            float fv[8] = {f0.x, f0.y, f0.z, f0.w, f1.x, f1.y, f1.z, f1.w};
            #pragma unroll
            for (int i = 0; i < 8; ++i)
                qf[ec][i] = (short)f2bf(fv[i] * SCL2E);
        }
    }

    f32x4 o[4];
    #pragma unroll
    for (int db = 0; db < 4; ++db)
        #pragma unroll
        for (int j = 0; j < 4; ++j) o[db][j] = 0.0f;
    float m_r[4] = {-INFINITY, -INFINITY, -INFINITY, -INFINITY};
    float l_r[4] = {0.f, 0.f, 0.f, 0.f};

    const int ntile = 2 * qt + 2;
    const int srow = tid >> 3;
    const int scc  = (tid & 7) * 8;

    for (int t = 0; t < ntile; ++t) {
        const int j0 = t * KVBLK;

        __syncthreads();
        {
            const float* kp = K + base + (size_t)(j0 + srow) * HE + scc;
            float4 a0 = *(const float4*)(kp);
            float4 a1 = *(const float4*)(kp + 4);
            float fv[8] = {a0.x, a0.y, a0.z, a0.w, a1.x, a1.y, a1.z, a1.w};
            short8 hv;
            #pragma unroll
            for (int i = 0; i < 8; ++i) hv[i] = (short)f2bf(fv[i]);
            *(short8*)(&Ks[srow * LDK + scc]) = hv;

            const float* vp = V + base + (size_t)(j0 + srow) * HE + scc;
            float4 b0 = *(const float4*)(vp);
            float4 b1 = *(const float4*)(vp + 4);
            float gv[8] = {b0.x, b0.y, b0.z, b0.w, b1.x, b1.y, b1.z, b1.w};
            #pragma unroll
            for (int i = 0; i < 8; ++i) {
                const int d = scc + i;
                const int col = srow ^ (((d >> 3) & 7) << 3);
                Vt[d * LDK + col] = (short)f2bf(gv[i]);
            }
        }
        __syncthreads();

        if (j0 <= q0 + 15) {
            const bool diag = (j0 + KVBLK - 1) > q0;

            f32x4 s[4];
            __builtin_amdgcn_s_setprio(1);
            #pragma unroll
            for (int kb = 0; kb < 4; ++kb) {
                f32x4 acc; acc[0]=0.f; acc[1]=0.f; acc[2]=0.f; acc[3]=0.f;
                const int roff = (kb * 16 + c) * LDK + 8 * g;
                short8 k0 = *(const short8*)(&Ks[roff]);
                short8 k1 = *(const short8*)(&Ks[roff + 32]);
                acc = MFMA(qf[0], k0, acc);
                acc = MFMA(qf[1], k1, acc);
                s[kb] = acc;
            }
            __builtin_amdgcn_s_setprio(0);

            float tm[4];
            #pragma unroll
            for (int r = 0; r < 4; ++r) {
                if (diag) {
                    const int qrow = q0 + 4 * g + r;
                    #pragma unroll
                    for (int kb = 0; kb < 4; ++kb)
                        if (j0 + kb * 16 + c > qrow) s[kb][r] = -INFINITY;
                }
                tm[r] = fmaxf(fmaxf(s[0][r], s[1][r]), fmaxf(s[2][r], s[3][r]));
                #pragma unroll
                for (int xm = 1; xm <= 8; xm <<= 1)
                    tm[r] = fmaxf(tm[r], __shfl_xor(tm[r], xm));
            }

            #pragma unroll
            for (int r = 0; r < 4; ++r) {
                const float nm = fmaxf(m_r[r], tm[r]);
                if (nm - m_r[r] > DEFER_THR) {
                    const float corr = __builtin_amdgcn_exp2f(m_r[r] - nm);
                    l_r[r] *= corr;
                    #pragma unroll
                    for (int db = 0; db < 4; ++db) o[db][r] *= corr;
                    m_r[r] = nm;
                }
                #pragma unroll
                for (int kb = 0; kb < 4; ++kb) {
                    const float p = __builtin_amdgcn_exp2f(s[kb][r] - m_r[r]);
                    l_r[r] += p;
                    Pl[(wave * 16 + 4 * g + r) * LDK + kb * 16 + c] = (short)f2bf(p);
                }
            }

            #pragma unroll
            for (int kc = 0; kc < 2; ++kc) {
                short8 pa = *(const short8*)(&Pl[(wave * 16 + c) * LDK + kc * 32 + 8 * g]);
                __builtin_amdgcn_s_setprio(1);
                #pragma unroll
                for (int db = 0; db < 4; ++db) {
                    const int d  = db * 16 + c;
                    const int k0 = (kc * 32 + 8 * g) ^ (((d >> 3) & 7) << 3);
                    short8 vb = *(const short8*)(&Vt[d * LDK + k0]);
                    o[db] = MFMA(pa, vb, o[db]);
                }
                __builtin_amdgcn_s_setprio(0);
            }
        }
    }

    #pragma unroll
    for (int r = 0; r < 4; ++r) {
        float ls = l_r[r];
        #pragma unroll
        for (int xm = 1; xm <= 8; xm <<= 1) ls += __shfl_xor(ls, xm);
        const float inv = 1.0f / ls;
        float* op = O + base + (size_t)(q0 + 4 * g + r) * HE + c;
        #pragma unroll
        for (int db = 0; db < 4; ++db)
            op[db * 16] = o[db][r] * inv;
    }
}

extern "C" void kernel_launch(void* const* d_in, const int* in_sizes, int n_in,
                              void* d_out, int out_size, void* d_ws, size_t ws_size,
                              hipStream_t stream) {
    const float* Q = (const float*)d_in[0];
    const float* K = (const float*)d_in[1];
    const float* V = (const float*)d_in[2];
    float* Out = (float*)d_out;

    const size_t kv_shorts = (size_t)64 * NT * 64 * 64;        // 8,388,608 per tensor
    const size_t need = 2 * kv_shorts * sizeof(short);         // 32 MiB

    if (ws_size >= need) {
        short* Kw = (short*)d_ws;
        short* Vw = Kw + kv_shorts;
        hipLaunchKernelGGL(prepass_cvt, dim3(64 * NT), dim3(512), 0, stream, K, V, Kw, Vw);
        hipLaunchKernelGGL(attn_fast, dim3(BB * HH * NQT), dim3(512), 0, stream, Q, Kw, Vw, Out);
    } else {
        hipLaunchKernelGGL(attn_mfma, dim3(BB * HH * NQT), dim3(512), 0, stream, Q, K, V, Out);
    }
}

// Round 13
// 210.956 us; speedup vs baseline: 1.5619x; 1.0096x over previous
//
#include <hip/hip_runtime.h>
#include <math.h>

// Problem constants: B=4, L=S=2048, H=16, E=D=64.
#define BB 4
#define LL 2048
#define HH 16
#define EE 64
#define HE (HH*EE)   // 1024 elements per (b,l) row

constexpr int QBLK  = 128;   // q rows per block (8 waves x 16 rows)
constexpr int KVBLK = 64;    // keys per LDS tile
constexpr int NW    = 8;     // waves per block
constexpr int NQT   = LL / QBLK;  // 16
constexpr int NT    = LL / KVBLK; // 32 KV tiles per (b,h)
constexpr int LDK   = 72;    // Pl LDS row stride in shorts (64 + 8 pad)
constexpr float SCL2E = 0.18033688011112042f; // (1/sqrt(64)) * log2(e)
constexpr float DEFER_THR = 8.0f;  // defer-max threshold (exp2 domain): P <= 2^8

typedef short short8 __attribute__((ext_vector_type(8)));
typedef float f32x4  __attribute__((ext_vector_type(4)));

#define MFMA(a, b, c) __builtin_amdgcn_mfma_f32_16x16x32_bf16((a), (b), (c), 0, 0, 0)

// global_load_lds: 16B per lane, per-lane GLOBAL addr, wave-uniform LDS base
// (writes lds_base + lane*16). Swizzle pre-applied to the SOURCE (G21).
#define GLD_LDS16(gp, lp)                                                     \
    __builtin_amdgcn_global_load_lds(                                         \
        (const __attribute__((address_space(1))) void*)(gp),                  \
        (__attribute__((address_space(3))) void*)(lp), 16, 0, 0)

static __device__ __forceinline__ unsigned short f2bf(float f) {
    unsigned u = __float_as_uint(f);
    return (unsigned short)((u + 0x7FFFu + ((u >> 16) & 1u)) >> 16);  // RNE
}

// HW packed fp32->bf16 RNE convert (no builtin on gfx950; guide T12 recipe).
static __device__ __forceinline__ unsigned cvt_pk_bf16(float lo, float hi) {
    unsigned r;
    asm("v_cvt_pk_bf16_f32 %0, %1, %2" : "=v"(r) : "v"(lo), "v"(hi));
    return r;
}

// ---------------------------------------------------------------------------
// Prepass: K -> bf16, XOR-pre-swizzled, tiled [bh][t][key][e'];
//          V -> bf16, tile-TRANSPOSED [bh][t][d][key'], same pre-swizzle.
// ---------------------------------------------------------------------------
__global__ __launch_bounds__(512, 2)
void prepass_cvt(const float* __restrict__ K, const float* __restrict__ V,
                 short* __restrict__ Kw, short* __restrict__ Vw)
{
    __shared__ short Vs[KVBLK][74];      // [key][d], pad 74 to spread banks
    const int bid = blockIdx.x;          // bh*NT + t
    const int bh  = bid >> 5, t = bid & 31;
    const int b   = bh >> 4, h = bh & 15;
    const int j0  = t * KVBLK;
    const int tid = threadIdx.x;
    const int row = tid >> 3;            // key (phase 1) / d (phase 2), 0..63
    const int ch8 = (tid & 7) * 8;       // 8-elem chunk
    const size_t gbase = (size_t)b * LL * HE + (size_t)h * EE;
    const size_t obase = (size_t)bid * (64 * 64);   // 4096 shorts per tile

    {
        const float* kp = K + gbase + (size_t)(j0 + row) * HE + ch8;
        float4 a0 = *(const float4*)kp, a1 = *(const float4*)(kp + 4);
        float fv[8] = {a0.x,a0.y,a0.z,a0.w,a1.x,a1.y,a1.z,a1.w};
        short8 hv;
        #pragma unroll
        for (int i = 0; i < 8; ++i) hv[i] = (short)f2bf(fv[i]);
        *(short8*)(Kw + obase + row * 64 + (ch8 ^ ((row & 7) * 8))) = hv;
    }
    {
        const float* vp = V + gbase + (size_t)(j0 + row) * HE + ch8;
        float4 b0 = *(const float4*)vp, b1 = *(const float4*)(vp + 4);
        float gv[8] = {b0.x,b0.y,b0.z,b0.w,b1.x,b1.y,b1.z,b1.w};
        short8 vv;
        #pragma unroll
        for (int i = 0; i < 8; ++i) vv[i] = (short)f2bf(gv[i]);
        *(short8*)(&Vs[row][ch8]) = vv;
    }
    __syncthreads();
    {
        short8 ov;
        #pragma unroll
        for (int i = 0; i < 8; ++i) ov[i] = Vs[ch8 + i][row];
        *(short8*)(Vw + obase + row * 64 + (ch8 ^ ((row & 7) * 8))) = ov;
    }
}

// ---------------------------------------------------------------------------
// Main: causal flash attention, bf16 MFMA. Double-buffered K/V staging
// (T3 2-phase: stage t+1 issued BEFORE compute t, ONE barrier per tile ->
// load latency hides under compute). P-convert via v_cvt_pk_bf16_f32.
// ---------------------------------------------------------------------------
__global__ __launch_bounds__(512, 4)
void attn_fast(const float* __restrict__ Q, const short* __restrict__ Kw,
               const short* __restrict__ Vw, float* __restrict__ O)
{
    __shared__ alignas(16) short Ks[2][KVBLK * 64]; // dbuf [key][e'] swizzled
    __shared__ alignas(16) short Vt[2][EE * 64];    // dbuf [d][key'] swizzled
    __shared__ short Pl[NW * 16 * LDK];             // per-wave P, [q][key]

    const int bid = blockIdx.x;
    const int qt  = (NQT - 1) - (bid >> 6);       // descending work order
    const int bh  = bid & 63;
    const int b   = bh >> 4, h = bh & 15;
    const size_t base = (size_t)b * LL * HE + (size_t)h * EE;

    const int tid  = threadIdx.x;
    const int wave = tid >> 6, lane = tid & 63;
    const int g    = lane >> 4, c = lane & 15;    // quarter-wave group, col lane
    const int swz  = (c & 7) * 8;                 // read-side XOR (matches prepass)

    const int q0 = qt * QBLK + wave * 16;         // this wave's first q row
    const size_t kvbase = (size_t)bh * (NT * 64 * 64);
    const size_t lane8  = (size_t)(wave * 64 + lane) * 8;  // staging offset, shorts

    // ---- Q fragment in registers: A-frag lane holds Q[q0 + c][ec*32 + 8g + i]
    short8 qf[2];
    {
        const float* qp = Q + base + (size_t)(q0 + c) * HE + 8 * g;
        #pragma unroll
        for (int ec = 0; ec < 2; ++ec) {
            float4 f0 = *(const float4*)(qp + ec * 32);
            float4 f1 = *(const float4*)(qp + ec * 32 + 4);
            float fv[8] = {f0.x, f0.y, f0.z, f0.w, f1.x, f1.y, f1.z, f1.w};
            #pragma unroll
            for (int i = 0; i < 8; ++i)
                qf[ec][i] = (short)f2bf(fv[i] * SCL2E);
        }
    }

    f32x4 o[4];
    #pragma unroll
    for (int db = 0; db < 4; ++db)
        #pragma unroll
        for (int j = 0; j < 4; ++j) o[db][j] = 0.0f;
    float m_r[4] = {-INFINITY, -INFINITY, -INFINITY, -INFINITY};
    float l_r[4] = {0.f, 0.f, 0.f, 0.f};

    const int ntile = 2 * qt + 2;

    // ---- prologue: stage tile 0 into buffer 0 (all waves, uniform)
    GLD_LDS16(Kw + kvbase + lane8, &Ks[0][wave * 512]);
    GLD_LDS16(Vw + kvbase + lane8, &Vt[0][wave * 512]);

    int cur = 0;
    for (int t = 0; t < ntile; ++t) {
        const int j0 = t * KVBLK;

        // ONE barrier per tile: drains vmcnt -> buf[cur] (staged a full
        // compute-phase ago) is ready; all waves done with buf[cur^1].
        __syncthreads();

        // ---- issue stage of t+1 into the buffer just freed (overlaps compute)
        if (t + 1 < ntile) {
            const size_t goff = kvbase + (size_t)(t + 1) * 4096 + lane8;
            GLD_LDS16(Kw + goff, &Ks[cur ^ 1][wave * 512]);
            GLD_LDS16(Vw + goff, &Vt[cur ^ 1][wave * 512]);
        }

        if (j0 <= q0 + 15) {                        // else: this wave fully masked
            const bool diag = (j0 + KVBLK - 1) > q0;
            const short* ksb = &Ks[cur][0];
            const short* vtb = &Vt[cur][0];

            // ---- QK^T: S[16q x 64k], D-layout row=4g+r, col=c
            f32x4 s[4];
            __builtin_amdgcn_s_setprio(1);
            #pragma unroll
            for (int kb = 0; kb < 4; ++kb) {
                f32x4 acc; acc[0]=0.f; acc[1]=0.f; acc[2]=0.f; acc[3]=0.f;
                const int roff = (kb * 16 + c) * 64;
                short8 k0 = *(const short8*)(&ksb[roff + ((8 * g) ^ swz)]);
                short8 k1 = *(const short8*)(&ksb[roff + ((32 + 8 * g) ^ swz)]);
                acc = MFMA(qf[0], k0, acc);
                acc = MFMA(qf[1], k1, acc);
                s[kb] = acc;
            }
            __builtin_amdgcn_s_setprio(0);

            // ---- mask + row max (nested fmaxf -> v_max3 fusion)
            float tm[4];
            #pragma unroll
            for (int r = 0; r < 4; ++r) {
                if (diag) {
                    const int qrow = q0 + 4 * g + r;
                    #pragma unroll
                    for (int kb = 0; kb < 4; ++kb)
                        if (j0 + kb * 16 + c > qrow) s[kb][r] = -INFINITY;
                }
                tm[r] = fmaxf(fmaxf(fmaxf(s[0][r], s[1][r]), s[2][r]), s[3][r]);
                #pragma unroll
                for (int xm = 1; xm <= 8; xm <<= 1)
                    tm[r] = fmaxf(tm[r], __shfl_xor(tm[r], xm));
            }

            // ---- online softmax (defer-max) + P->bf16 via cvt_pk -> LDS
            #pragma unroll
            for (int r = 0; r < 4; ++r) {
                const float nm = fmaxf(m_r[r], tm[r]);
                if (nm - m_r[r] > DEFER_THR) {       // rescale (rare after tile 0)
                    const float corr = __builtin_amdgcn_exp2f(m_r[r] - nm); // -inf -> 0
                    l_r[r] *= corr;
                    #pragma unroll
                    for (int db = 0; db < 4; ++db) o[db][r] *= corr;
                    m_r[r] = nm;
                }
                const float p0 = __builtin_amdgcn_exp2f(s[0][r] - m_r[r]);
                const float p1 = __builtin_amdgcn_exp2f(s[1][r] - m_r[r]);
                const float p2 = __builtin_amdgcn_exp2f(s[2][r] - m_r[r]);
                const float p3 = __builtin_amdgcn_exp2f(s[3][r] - m_r[r]);
                l_r[r] += (p0 + p1) + (p2 + p3);     // fp32 denom (unrounded)
                const unsigned pk01 = cvt_pk_bf16(p0, p1);  // lo=p0, hi=p1
                const unsigned pk23 = cvt_pk_bf16(p2, p3);
                short* prow = &Pl[(wave * 16 + 4 * g + r) * LDK + c];
                prow[0]  = (short)pk01;
                prow[16] = (short)(pk01 >> 16);
                prow[32] = (short)pk23;
                prow[48] = (short)(pk23 >> 16);
            }

            // ---- PV: O[16q x 64d] += P * V   (A=P from LDS, B=V^T rows)
            #pragma unroll
            for (int kc = 0; kc < 2; ++kc) {
                short8 pa = *(const short8*)(&Pl[(wave * 16 + c) * LDK + kc * 32 + 8 * g]);
                __builtin_amdgcn_s_setprio(1);
                #pragma unroll
                for (int db = 0; db < 4; ++db) {
                    const int voff = (db * 16 + c) * 64 + ((kc * 32 + 8 * g) ^ swz);
                    short8 vb = *(const short8*)(&vtb[voff]);
                    o[db] = MFMA(pa, vb, o[db]);
                }
                __builtin_amdgcn_s_setprio(0);
            }
        }
        cur ^= 1;
    }

    // ---- epilogue: reduce denominator across key-lanes, normalize, store
    #pragma unroll
    for (int r = 0; r < 4; ++r) {
        float ls = l_r[r];
        #pragma unroll
        for (int xm = 1; xm <= 8; xm <<= 1) ls += __shfl_xor(ls, xm);
        const float inv = 1.0f / ls;
        float* op = O + base + (size_t)(q0 + 4 * g + r) * HE + c;
        #pragma unroll
        for (int db = 0; db < 4; ++db)
            op[db * 16] = o[db][r] * inv;
    }
}

// ---------------------------------------------------------------------------
// Fallback (round-10 kernel, measured 137us): used only if ws_size < 32 MiB.
// ---------------------------------------------------------------------------
__global__ __launch_bounds__(512, 4)
void attn_mfma(const float* __restrict__ Q, const float* __restrict__ K,
               const float* __restrict__ V, float* __restrict__ O)
{
    __shared__ short Ks[KVBLK * LDK];
    __shared__ short Vt[EE * LDK];
    __shared__ short Pl[NW * 16 * LDK];

    const int bid = blockIdx.x;
    const int qt  = (NQT - 1) - (bid >> 6);
    const int bh  = bid & 63;
    const int b   = bh >> 4, h = bh & 15;
    const size_t base = (size_t)b * LL * HE + (size_t)h * EE;

    const int tid  = threadIdx.x;
    const int wave = tid >> 6, lane = tid & 63;
    const int g    = lane >> 4, c = lane & 15;

    const int q0 = qt * QBLK + wave * 16;

    short8 qf[2];
    {
        const float* qp = Q + base + (size_t)(q0 + c) * HE + 8 * g;
        #pragma unroll
        for (int ec = 0; ec < 2; ++ec) {
            float4 f0 = *(const float4*)(qp + ec * 32);
            float4 f1 = *(const float4*)(qp + ec * 32 + 4);
            float fv[8] = {f0.x, f0.y, f0.z, f0.w, f1.x, f1.y, f1.z, f1.w};
            #pragma unroll
            for (int i = 0; i < 8; ++i)
                qf[ec][i] = (short)f2bf(fv[i] * SCL2E);
        }
    }

    f32x4 o[4];
    #pragma unroll
    for (int db = 0; db < 4; ++db)
        #pragma unroll
        for (int j = 0; j < 4; ++j) o[db][j] = 0.0f;
    float m_r[4] = {-INFINITY, -INFINITY, -INFINITY, -INFINITY};
    float l_r[4] = {0.f, 0.f, 0.f, 0.f};

    const int ntile = 2 * qt + 2;
    const int srow = tid >> 3;
    const int scc  = (tid & 7) * 8;

    for (int t = 0; t < ntile; ++t) {
        const int j0 = t * KVBLK;

        __syncthreads();
        {
            const float* kp = K + base + (size_t)(j0 + srow) * HE + scc;
            float4 a0 = *(const float4*)(kp);
            float4 a1 = *(const float4*)(kp + 4);
            float fv[8] = {a0.x, a0.y, a0.z, a0.w, a1.x, a1.y, a1.z, a1.w};
            short8 hv;
            #pragma unroll
            for (int i = 0; i < 8; ++i) hv[i] = (short)f2bf(fv[i]);
            *(short8*)(&Ks[srow * LDK + scc]) = hv;

            const float* vp = V + base + (size_t)(j0 + srow) * HE + scc;
            float4 b0 = *(const float4*)(vp);
            float4 b1 = *(const float4*)(vp + 4);
            float gv[8] = {b0.x, b0.y, b0.z, b0.w, b1.x, b1.y, b1.z, b1.w};
            #pragma unroll
            for (int i = 0; i < 8; ++i) {
                const int d = scc + i;
                const int col = srow ^ (((d >> 3) & 7) << 3);
                Vt[d * LDK + col] = (short)f2bf(gv[i]);
            }
        }
        __syncthreads();

        if (j0 <= q0 + 15) {
            const bool diag = (j0 + KVBLK - 1) > q0;

            f32x4 s[4];
            __builtin_amdgcn_s_setprio(1);
            #pragma unroll
            for (int kb = 0; kb < 4; ++kb) {
                f32x4 acc; acc[0]=0.f; acc[1]=0.f; acc[2]=0.f; acc[3]=0.f;
                const int roff = (kb * 16 + c) * LDK + 8 * g;
                short8 k0 = *(const short8*)(&Ks[roff]);
                short8 k1 = *(const short8*)(&Ks[roff + 32]);
                acc = MFMA(qf[0], k0, acc);
                acc = MFMA(qf[1], k1, acc);
                s[kb] = acc;
            }
            __builtin_amdgcn_s_setprio(0);

            float tm[4];
            #pragma unroll
            for (int r = 0; r < 4; ++r) {
                if (diag) {
                    const int qrow = q0 + 4 * g + r;
                    #pragma unroll
                    for (int kb = 0; kb < 4; ++kb)
                        if (j0 + kb * 16 + c > qrow) s[kb][r] = -INFINITY;
                }
                tm[r] = fmaxf(fmaxf(s[0][r], s[1][r]), fmaxf(s[2][r], s[3][r]));
                #pragma unroll
                for (int xm = 1; xm <= 8; xm <<= 1)
                    tm[r] = fmaxf(tm[r], __shfl_xor(tm[r], xm));
            }

            #pragma unroll
            for (int r = 0; r < 4; ++r) {
                const float nm = fmaxf(m_r[r], tm[r]);
                if (nm - m_r[r] > DEFER_THR) {
                    const float corr = __builtin_amdgcn_exp2f(m_r[r] - nm);
                    l_r[r] *= corr;
                    #pragma unroll
                    for (int db = 0; db < 4; ++db) o[db][r] *= corr;
                    m_r[r] = nm;
                }
                #pragma unroll
                for (int kb = 0; kb < 4; ++kb) {
                    const float p = __builtin_amdgcn_exp2f(s[kb][r] - m_r[r]);
                    l_r[r] += p;
                    Pl[(wave * 16 + 4 * g + r) * LDK + kb * 16 + c] = (short)f2bf(p);
                }
            }

            #pragma unroll
            for (int kc = 0; kc < 2; ++kc) {
                short8 pa = *(const short8*)(&Pl[(wave * 16 + c) * LDK + kc * 32 + 8 * g]);
                __builtin_amdgcn_s_setprio(1);
                #pragma unroll
                for (int db = 0; db < 4; ++db) {
                    const int d  = db * 16 + c;
                    const int k0 = (kc * 32 + 8 * g) ^ (((d >> 3) & 7) << 3);
                    short8 vb = *(const short8*)(&Vt[d * LDK + k0]);
                    o[db] = MFMA(pa, vb, o[db]);
                }
                __builtin_amdgcn_s_setprio(0);
            }
        }
    }

    #pragma unroll
    for (int r = 0; r < 4; ++r) {
        float ls = l_r[r];
        #pragma unroll
        for (int xm = 1; xm <= 8; xm <<= 1) ls += __shfl_xor(ls, xm);
        const float inv = 1.0f / ls;
        float* op = O + base + (size_t)(q0 + 4 * g + r) * HE + c;
        #pragma unroll
        for (int db = 0; db < 4; ++db)
            op[db * 16] = o[db][r] * inv;
    }
}

extern "C" void kernel_launch(void* const* d_in, const int* in_sizes, int n_in,
                              void* d_out, int out_size, void* d_ws, size_t ws_size,
                              hipStream_t stream) {
    const float* Q = (const float*)d_in[0];
    const float* K = (const float*)d_in[1];
    const float* V = (const float*)d_in[2];
    float* Out = (float*)d_out;

    const size_t kv_shorts = (size_t)64 * NT * 64 * 64;        // 8,388,608 per tensor
    const size_t need = 2 * kv_shorts * sizeof(short);         // 32 MiB

    if (ws_size >= need) {
        short* Kw = (short*)d_ws;
        short* Vw = Kw + kv_shorts;
        hipLaunchKernelGGL(prepass_cvt, dim3(64 * NT), dim3(512), 0, stream, K, V, Kw, Vw);
        hipLaunchKernelGGL(attn_fast, dim3(BB * HH * NQT), dim3(512), 0, stream, Q, Kw, Vw, Out);
    } else {
        hipLaunchKernelGGL(attn_mfma, dim3(BB * HH * NQT), dim3(512), 0, stream, Q, K, V, Out);
    }
}